// Round 2
// baseline (19010.606 us; speedup 1.0000x reference)
//
#include <hip/hip_runtime.h>
#include <math.h>

#define B_   16
#define S_   1024
#define R_   512
#define H_   512
#define HD_  256
#define G_   1024
#define DIN_ 1536

// ---------------------------------------------------------------------------
// Tiled fp32 GEMM:  C[m][n] = sum_k A(m,k) * B(n,k)
// A layout MK (row-major [M][K], row stride a_rs), optional row remap for step1.
// B layout NK (row-major [N][K], row stride b_rs).
// EPI: 0 = none, 1 = tanh(x + bias[n]), 2 = x + bias[n] + bias2[n]
// ---------------------------------------------------------------------------
template<int EPI, int REMAP_A>
__global__ __launch_bounds__(256) void gemm_mk_nk(
    const float* __restrict__ A, long a_rs, long a_bs,
    const float* __restrict__ Bm, long b_rs, long b_bs,
    float* __restrict__ C, long c_rs, long c_bs,
    const float* __restrict__ bias, const float* __restrict__ bias2,
    int M, int N, int K)
{
    __shared__ float As[16][68];
    __shared__ float Bs[16][68];
    const int bb = blockIdx.z;
    const float* Ab = A + (long)bb * a_bs;
    const float* Bb = Bm + (long)bb * b_bs;
    float* Cb = C + (long)bb * c_bs;
    const int m0 = blockIdx.y * 64, n0 = blockIdx.x * 64;
    const int tid = threadIdx.x;
    const int tx = tid & 15, ty = tid >> 4;
    const int lr = tid >> 2;          // tile row 0..63
    const int lk = (tid & 3) << 2;    // k offset 0..12

    long arow;
    {
        int m = m0 + lr;
        if (REMAP_A) arow = (long)((m % S_) * B_ + (m / S_)) * a_rs;
        else         arow = (long)m * a_rs;
    }
    const long brow = (long)(n0 + lr) * b_rs;

    float acc[4][4] = {};
    for (int k0 = 0; k0 < K; k0 += 16) {
        float4 av = *(const float4*)(Ab + arow + k0 + lk);
        float4 bv = *(const float4*)(Bb + brow + k0 + lk);
        As[lk + 0][lr] = av.x; As[lk + 1][lr] = av.y;
        As[lk + 2][lr] = av.z; As[lk + 3][lr] = av.w;
        Bs[lk + 0][lr] = bv.x; Bs[lk + 1][lr] = bv.y;
        Bs[lk + 2][lr] = bv.z; Bs[lk + 3][lr] = bv.w;
        __syncthreads();
#pragma unroll
        for (int kk = 0; kk < 16; ++kk) {
            float4 a = *(const float4*)&As[kk][ty << 2];
            float4 b = *(const float4*)&Bs[kk][tx << 2];
            acc[0][0] += a.x * b.x; acc[0][1] += a.x * b.y; acc[0][2] += a.x * b.z; acc[0][3] += a.x * b.w;
            acc[1][0] += a.y * b.x; acc[1][1] += a.y * b.y; acc[1][2] += a.y * b.z; acc[1][3] += a.y * b.w;
            acc[2][0] += a.z * b.x; acc[2][1] += a.z * b.y; acc[2][2] += a.z * b.z; acc[2][3] += a.z * b.w;
            acc[3][0] += a.w * b.x; acc[3][1] += a.w * b.y; acc[3][2] += a.w * b.z; acc[3][3] += a.w * b.w;
        }
        __syncthreads();
    }
#pragma unroll
    for (int i = 0; i < 4; ++i) {
        const int m = m0 + (ty << 2) + i;
#pragma unroll
        for (int j = 0; j < 4; ++j) {
            const int n = n0 + (tx << 2) + j;
            float v = acc[i][j];
            if (EPI == 1) v = tanhf(v + bias[n]);
            else if (EPI == 2) v += bias[n] + bias2[n];
            Cb[(long)m * c_rs + n] = v;
        }
    }
}

// ---------------------------------------------------------------------------
// Tiled fp32 GEMM:  C[m][n] = sum_k A(k,m) * B(n,k)
// A layout KM ([K][M], k stride a_ks), B layout NK.  No epilogue.
// ---------------------------------------------------------------------------
__global__ __launch_bounds__(256) void gemm_km_nk(
    const float* __restrict__ A, long a_ks, long a_bs,
    const float* __restrict__ Bm, long b_rs, long b_bs,
    float* __restrict__ C, long c_rs, long c_bs,
    int M, int N, int K)
{
    __shared__ float As[16][68];
    __shared__ float Bs[16][68];
    const int bb = blockIdx.z;
    const float* Ab = A + (long)bb * a_bs;
    const float* Bb = Bm + (long)bb * b_bs;
    float* Cb = C + (long)bb * c_bs;
    const int m0 = blockIdx.y * 64, n0 = blockIdx.x * 64;
    const int tid = threadIdx.x;
    const int tx = tid & 15, ty = tid >> 4;
    const int lr = tid >> 2;            // B tile row (n) 0..63
    const int lk = (tid & 3) << 2;      // B k offset
    const int alk = tid >> 4;           // A k row 0..15
    const int alm = (tid & 15) << 2;    // A m offset
    const long brow = (long)(n0 + lr) * b_rs;

    float acc[4][4] = {};
    for (int k0 = 0; k0 < K; k0 += 16) {
        float4 av = *(const float4*)(Ab + (long)(k0 + alk) * a_ks + m0 + alm);
        *(float4*)&As[alk][alm] = av;
        float4 bv = *(const float4*)(Bb + brow + k0 + lk);
        Bs[lk + 0][lr] = bv.x; Bs[lk + 1][lr] = bv.y;
        Bs[lk + 2][lr] = bv.z; Bs[lk + 3][lr] = bv.w;
        __syncthreads();
#pragma unroll
        for (int kk = 0; kk < 16; ++kk) {
            float4 a = *(const float4*)&As[kk][ty << 2];
            float4 b = *(const float4*)&Bs[kk][tx << 2];
            acc[0][0] += a.x * b.x; acc[0][1] += a.x * b.y; acc[0][2] += a.x * b.z; acc[0][3] += a.x * b.w;
            acc[1][0] += a.y * b.x; acc[1][1] += a.y * b.y; acc[1][2] += a.y * b.z; acc[1][3] += a.y * b.w;
            acc[2][0] += a.z * b.x; acc[2][1] += a.z * b.y; acc[2][2] += a.z * b.z; acc[2][3] += a.z * b.w;
            acc[3][0] += a.w * b.x; acc[3][1] += a.w * b.y; acc[3][2] += a.w * b.z; acc[3][3] += a.w * b.w;
        }
        __syncthreads();
    }
#pragma unroll
    for (int i = 0; i < 4; ++i) {
        const int m = m0 + (ty << 2) + i;
#pragma unroll
        for (int j = 0; j < 4; ++j) {
            const int n = n0 + (tx << 2) + j;
            Cb[(long)m * c_rs + n] = acc[i][j];
        }
    }
}

// ---------------------------------------------------------------------------
// Softmax over r (last axis, contiguous, 512 elems): one wave per row, in-place
// ---------------------------------------------------------------------------
__global__ __launch_bounds__(256) void softmax_rows(float* __restrict__ l)
{
    const int lane = threadIdx.x & 63;
    const int wv = threadIdx.x >> 6;
    const long row = (long)blockIdx.x * 4 + wv;
    float* p = l + row * R_;
    float4 v0 = ((const float4*)p)[lane * 2];
    float4 v1 = ((const float4*)p)[lane * 2 + 1];
    float m = fmaxf(fmaxf(fmaxf(v0.x, v0.y), fmaxf(v0.z, v0.w)),
                    fmaxf(fmaxf(v1.x, v1.y), fmaxf(v1.z, v1.w)));
#pragma unroll
    for (int o = 32; o; o >>= 1) m = fmaxf(m, __shfl_xor(m, o));
    v0.x = __expf(v0.x - m); v0.y = __expf(v0.y - m);
    v0.z = __expf(v0.z - m); v0.w = __expf(v0.w - m);
    v1.x = __expf(v1.x - m); v1.y = __expf(v1.y - m);
    v1.z = __expf(v1.z - m); v1.w = __expf(v1.w - m);
    float s = v0.x + v0.y + v0.z + v0.w + v1.x + v1.y + v1.z + v1.w;
#pragma unroll
    for (int o = 32; o; o >>= 1) s += __shfl_xor(s, o);
    const float inv = 1.f / s;
    v0.x *= inv; v0.y *= inv; v0.z *= inv; v0.w *= inv;
    v1.x *= inv; v1.y *= inv; v1.z *= inv; v1.w *= inv;
    ((float4*)p)[lane * 2] = v0;
    ((float4*)p)[lane * 2 + 1] = v1;
}

// ---------------------------------------------------------------------------
// Softmax over s (axis 1, stride R): 512 threads = 128 cols x 4 s-groups,
// LDS reduce across the 4 partials, 3 coalesced passes.
// ---------------------------------------------------------------------------
__global__ __launch_bounds__(512) void softmax_cols(const float* __restrict__ l,
                                                    float* __restrict__ as_)
{
    const int b = blockIdx.y;
    const int rl = threadIdx.x & 127;
    const int r = blockIdx.x * 128 + rl;
    const int sg = threadIdx.x >> 7;           // 0..3
    const int s0 = sg * (S_ / 4), s1 = s0 + S_ / 4;
    const float* base = l + (long)b * S_ * R_ + r;
    __shared__ float red[4][128];

    float pm = -1e30f;
    for (int s = s0; s < s1; ++s) pm = fmaxf(pm, base[(long)s * R_]);
    red[sg][rl] = pm;
    __syncthreads();
    const float m = fmaxf(fmaxf(red[0][rl], red[1][rl]), fmaxf(red[2][rl], red[3][rl]));
    __syncthreads();

    float ps = 0.f;
    for (int s = s0; s < s1; ++s) ps += __expf(base[(long)s * R_] - m);
    red[sg][rl] = ps;
    __syncthreads();
    const float inv = 1.f / (red[0][rl] + red[1][rl] + red[2][rl] + red[3][rl]);

    float* ob = as_ + (long)b * S_ * R_ + r;
    for (int s = s0; s < s1; ++s) ob[(long)s * R_] = __expf(base[(long)s * R_] - m) * inv;
}

// ---------------------------------------------------------------------------
// cat[b][h][s] = h_s[b][s][h]  (s_t half of cat_sc), 32x32 LDS tile transpose
// ---------------------------------------------------------------------------
__global__ __launch_bounds__(256) void transpose_hs(const float* __restrict__ hs,
                                                    float* __restrict__ cat)
{
    __shared__ float tile[32][33];
    const int b = blockIdx.z;
    const int s0 = blockIdx.x * 32, h0 = blockIdx.y * 32;
    const int tx = threadIdx.x, ty = threadIdx.y;
#pragma unroll
    for (int i = 0; i < 32; i += 8)
        tile[ty + i][tx] = hs[((long)b * S_ + s0 + ty + i) * H_ + h0 + tx];
    __syncthreads();
#pragma unroll
    for (int i = 0; i < 32; i += 8)
        cat[((long)b * 2 * H_ + h0 + ty + i) * S_ + s0 + tx] = tile[tx][ty + i];
}

// ---------------------------------------------------------------------------
// bin[t][b][0:1024] = c_r[b][t][:]; bin[t][b][1024:1536] = ref[t][b][:]
// ---------------------------------------------------------------------------
__global__ __launch_bounds__(256) void build_bin(const float* __restrict__ cr,
                                                 const float* __restrict__ ref,
                                                 float* __restrict__ bin)
{
    const long idx4 = (long)blockIdx.x * blockDim.x + threadIdx.x;
    if (idx4 >= (long)R_ * B_ * DIN_ / 4) return;
    const long f = idx4 * 4;
    const int d = (int)(f % DIN_);
    const long tb = f / DIN_;
    const int b = (int)(tb % B_);
    const int t = (int)(tb / B_);
    float4 v;
    if (d < 2 * H_) v = *(const float4*)(cr + ((long)b * R_ + t) * (2 * H_) + d);
    else            v = *(const float4*)(ref + ((long)t * B_ + b) * H_ + (d - 2 * H_));
    *(float4*)(bin + f) = v;
}

// ---------------------------------------------------------------------------
// Cooperative bi-LSTM scan. 64 blocks/dir x 512 threads.
// Block (dir, j) owns 16 gate rows [j*16, j*16+16) of W_hh in LDS.
// Thread = (kh = tid&1, b = (tid>>1)&15, g = tid>>5): half-K dot + pair shfl.
// Per step: phase A computes its gate slice -> global gbuf (double-buffered),
// device barrier (per direction), phase B: every block redundantly applies the
// full elementwise cell update, keeping h in LDS and c in registers.
// W reads are 4-address 16-way broadcasts; xg is prefetched one step ahead.
// ---------------------------------------------------------------------------
#define NBLK_DIR 64

__device__ inline float sig_(float x) { return 1.f / (1.f + __expf(-x)); }
__device__ inline float tanh_(float x) {
    float ax = fabsf(x);
    float t = 1.f - 2.f / (1.f + __expf(2.f * ax));
    return copysignf(t, x);
}

__device__ inline void dirBarrier(unsigned* bar, int nblocks)
{
    __syncthreads();
    if (threadIdx.x == 0) {
        unsigned gen = __hip_atomic_load(bar + 1, __ATOMIC_RELAXED, __HIP_MEMORY_SCOPE_AGENT);
        unsigned old = __hip_atomic_fetch_add(bar, 1u, __ATOMIC_ACQ_REL, __HIP_MEMORY_SCOPE_AGENT);
        if (old == (unsigned)(nblocks - 1)) {
            __hip_atomic_store(bar, 0u, __ATOMIC_RELAXED, __HIP_MEMORY_SCOPE_AGENT);
            __hip_atomic_fetch_add(bar + 1, 1u, __ATOMIC_RELEASE, __HIP_MEMORY_SCOPE_AGENT);
        } else {
            while (__hip_atomic_load(bar + 1, __ATOMIC_ACQUIRE, __HIP_MEMORY_SCOPE_AGENT) == gen)
                __builtin_amdgcn_s_sleep(2);
        }
    }
    __syncthreads();
}

__global__ __launch_bounds__(512) void lstm_scan(
    const float* __restrict__ xg_f, const float* __restrict__ xg_b,
    const float* __restrict__ Whh_f, const float* __restrict__ Whh_b,
    float* __restrict__ out, float* __restrict__ gbuf, unsigned* __restrict__ bar)
{
    const int blk = blockIdx.x;
    const int dir = blk >> 6;
    const int j = blk & 63;
    const float* xg = dir ? xg_b : xg_f;
    const float* Whh = dir ? Whh_b : Whh_f;
    float* gb = gbuf + dir * (2 * B_ * G_);
    unsigned* mybar = bar + dir * 64;

    __shared__ float W_lds[16][260];
    __shared__ float h_lds[16][260];
    const int tid = threadIdx.x;
    const int g0 = j * 16;

    for (int idx = tid; idx < 16 * 64; idx += 512) {
        int row = idx >> 6, k4 = (idx & 63) << 2;
        *(float4*)&W_lds[row][k4] = *(const float4*)(Whh + (long)(g0 + row) * HD_ + k4);
        *(float4*)&h_lds[row][k4] = make_float4(0.f, 0.f, 0.f, 0.f);
    }
    float c_reg[8] = {0.f, 0.f, 0.f, 0.f, 0.f, 0.f, 0.f, 0.f};
    const int kh = tid & 1;                 // phase A: K half
    const int pa_b = (tid >> 1) & 15;       // phase A: batch
    const int pa_g = tid >> 5;              // phase A: gate row 0..15
    const int kbase = kh << 7;              // 0 or 128
    const long xg_off = (long)pa_b * G_ + g0 + pa_g;
    const int pb_b = tid >> 5, pb_j0 = (tid & 31) << 3;  // phase B: 8 h-elems
    __syncthreads();

    // prefetch xg for step 0
    float xg_next = 0.f;
    if (!kh) xg_next = xg[(long)(dir ? R_ - 1 : 0) * (B_ * G_) + xg_off];

    for (int t = 0; t < R_; ++t) {
        const int tt = dir ? (R_ - 1 - t) : t;
        float* gc = gb + (t & 1) * (B_ * G_);
        // phase A: gates slice = xg + h . Whh^T  (half-K per thread)
        float acc = xg_next;
        if (!kh && t + 1 < R_) {
            const int tn = dir ? (R_ - 2 - t) : (t + 1);
            xg_next = xg[(long)tn * (B_ * G_) + xg_off];
        }
#pragma unroll 8
        for (int k = 0; k < 128; k += 4) {
            float4 hv = *(const float4*)&h_lds[pa_b][kbase + k];
            float4 wv = *(const float4*)&W_lds[pa_g][kbase + k];
            acc += hv.x * wv.x + hv.y * wv.y + hv.z * wv.z + hv.w * wv.w;
        }
        acc += __shfl_xor(acc, 1);
        if (!kh) gc[pa_b * G_ + g0 + pa_g] = acc;
        __threadfence();
        dirBarrier(mybar, NBLK_DIR);
        // phase B: full cell update (replicated per block)
        const float* gr = gc + pb_b * G_ + pb_j0;
        float4 iv0 = *(const float4*)(gr + 0),        iv1 = *(const float4*)(gr + 4);
        float4 fv0 = *(const float4*)(gr + HD_),      fv1 = *(const float4*)(gr + HD_ + 4);
        float4 gv0 = *(const float4*)(gr + 2 * HD_),  gv1 = *(const float4*)(gr + 2 * HD_ + 4);
        float4 ov0 = *(const float4*)(gr + 3 * HD_),  ov1 = *(const float4*)(gr + 3 * HD_ + 4);
        float ia[8] = {iv0.x, iv0.y, iv0.z, iv0.w, iv1.x, iv1.y, iv1.z, iv1.w};
        float fa[8] = {fv0.x, fv0.y, fv0.z, fv0.w, fv1.x, fv1.y, fv1.z, fv1.w};
        float ga[8] = {gv0.x, gv0.y, gv0.z, gv0.w, gv1.x, gv1.y, gv1.z, gv1.w};
        float oa[8] = {ov0.x, ov0.y, ov0.z, ov0.w, ov1.x, ov1.y, ov1.z, ov1.w};
        float hv8[8];
#pragma unroll
        for (int e = 0; e < 8; ++e) {
            float ig = sig_(ia[e]);
            float fg = sig_(fa[e]);
            float gg = tanh_(ga[e]);
            float og = sig_(oa[e]);
            c_reg[e] = fg * c_reg[e] + ig * gg;
            hv8[e] = og * tanh_(c_reg[e]);
            h_lds[pb_b][pb_j0 + e] = hv8[e];
        }
        if (pb_b == j) {  // blocks j<16 write batch row b=j of the output
            float* op = out + ((long)tt * B_ + pb_b) * (2 * HD_) + dir * HD_ + pb_j0;
            *(float4*)op = make_float4(hv8[0], hv8[1], hv8[2], hv8[3]);
            *(float4*)(op + 4) = make_float4(hv8[4], hv8[5], hv8[6], hv8[7]);
        }
        __syncthreads();
    }
}

// ---------------------------------------------------------------------------
extern "C" void kernel_launch(void* const* d_in, const int* in_sizes, int n_in,
                              void* d_out, int out_size, void* d_ws, size_t ws_size,
                              hipStream_t stream)
{
    const float* src  = (const float*)d_in[1];   // [S][B][H]
    const float* ref  = (const float*)d_in[2];   // [R][B][H]
    const float* Wref = (const float*)d_in[3];   // [H][H]
    const float* bref = (const float*)d_in[4];   // [H]
    const float* Wihf = (const float*)d_in[5];   // [G][DIN]
    const float* Whhf = (const float*)d_in[6];   // [G][HD]
    const float* bihf = (const float*)d_in[7];
    const float* bhhf = (const float*)d_in[8];
    const float* Wihb = (const float*)d_in[9];
    const float* Whhb = (const float*)d_in[10];
    const float* bihb = (const float*)d_in[11];
    const float* bhhb = (const float*)d_in[12];
    float* out = (float*)d_out;                  // [R][B][2*HD]

    float* ws = (float*)d_ws;
    // workspace layout (floats), with aliasing (161 MiB total):
    float* hs  = ws + 0L;                         // 8388608   [B][S][H]
    float* l   = ws + 8388608L;                   // 8388608   [B][S][R] (a_r in place)
    float* as_ = ws + 16777216L;                  // 8388608   [B][S][R]
    float* cat = ws + 25165824L;                  // 16777216  [B][2H][S]
    float* cr  = hs;                              // 8388608   [B][R][2H]  (hs dead after step 4)
    float* bin = cat;                             // 12582912  [T][B][DIN] (cat dead after step 6)
    float* xgf = l;                               // 8388608   [T][B][G]   (l dead after step 6)
    float* xgb = as_;                             // 8388608   [T][B][G]   (as_ dead after step 5)
    float* gbuf = ws + 41943040L;                 // 65536     2 dir x 2 parity x [B][G]
    unsigned* bar = (unsigned*)(ws + 42008576L);  // 128 u32 barrier state

    hipMemsetAsync(bar, 0, 512, stream);

    // 1) h_s = tanh(src . Wref^T + bref)   [B*S, 512] k=512
    gemm_mk_nk<1, 1><<<dim3(8, 256, 1), 256, 0, stream>>>(
        src, H_, 0, Wref, H_, 0, hs, H_, 0, bref, nullptr, B_ * S_, H_, H_);

    // 2) l[b] = h_s[b] . h_r[b]^T   M=1024 N=512 K=512, batched over b
    gemm_mk_nk<0, 0><<<dim3(8, 16, B_), 256, 0, stream>>>(
        hs, H_, (long)S_ * H_, ref, (long)B_ * H_, H_, l, R_, (long)S_ * R_,
        nullptr, nullptr, S_, R_, H_);

    // 3) a_s = softmax over s (columns), then a_r = softmax over r in place
    softmax_cols<<<dim3(R_ / 128, B_), 512, 0, stream>>>(l, as_);
    softmax_rows<<<(B_ * S_) / 4, 256, 0, stream>>>(l);

    // 4) cat rows 0..511 = h_s transposed
    transpose_hs<<<dim3(S_ / 32, H_ / 32, B_), dim3(32, 8), 0, stream>>>(hs, cat);

    // 5) cat rows 512..1023: c_s[b,h,s] = sum_r ref[r,b,h]*a_s[b,s,r]
    gemm_km_nk<<<dim3(16, 8, B_), 256, 0, stream>>>(
        ref, (long)B_ * H_, H_, as_, R_, (long)S_ * R_,
        cat + (long)H_ * S_, S_, (long)2 * H_ * S_, H_, S_, R_);

    // 6) c_r[b,r,k] = sum_s cat[b,k,s]*a_r[b,s,r]   M=512 N=1024 K=1024
    gemm_km_nk<<<dim3(16, 8, B_), 256, 0, stream>>>(
        l, R_, (long)S_ * R_, cat, S_, (long)2 * H_ * S_,
        cr, 2 * H_, (long)R_ * 2 * H_, R_, 2 * H_, S_);

    // 7) bilstm_in
    build_bin<<<(R_ * B_ * DIN_ / 4 + 255) / 256, 256, 0, stream>>>(cr, ref, bin);

    // 8) xg = bin . W_ih^T + b_ih + b_hh  (both directions)
    gemm_mk_nk<2, 0><<<dim3(16, 128, 1), 256, 0, stream>>>(
        bin, DIN_, 0, Wihf, DIN_, 0, xgf, G_, 0, bihf, bhhf, R_ * B_, G_, DIN_);
    gemm_mk_nk<2, 0><<<dim3(16, 128, 1), 256, 0, stream>>>(
        bin, DIN_, 0, Wihb, DIN_, 0, xgb, G_, 0, bihb, bhhb, R_ * B_, G_, DIN_);

    // 9) cooperative bi-LSTM scan
    void* args[] = {(void*)&xgf, (void*)&xgb, (void*)&Whhf, (void*)&Whhb,
                    (void*)&out, (void*)&gbuf, (void*)&bar};
    hipLaunchCooperativeKernel((void*)lstm_scan, dim3(2 * NBLK_DIR), dim3(512),
                               args, 0, stream);
}

// Round 6
// 7916.998 us; speedup vs baseline: 2.4012x; 2.4012x over previous
//
#include <hip/hip_runtime.h>
#include <math.h>

#define B_   16
#define S_   1024
#define R_   512
#define H_   512
#define HD_  256
#define G_   1024
#define DIN_ 1536

// ---------------------------------------------------------------------------
// Tiled fp32 GEMM:  C[m][n] = sum_k A(m,k) * B(n,k)
// A layout MK (row-major [M][K], row stride a_rs), optional row remap for step1.
// B layout NK (row-major [N][K], row stride b_rs).
// EPI: 0 = none, 1 = tanh(x + bias[n]), 2 = x + bias[n] + bias2[n]
// ---------------------------------------------------------------------------
template<int EPI, int REMAP_A>
__global__ __launch_bounds__(256) void gemm_mk_nk(
    const float* __restrict__ A, long a_rs, long a_bs,
    const float* __restrict__ Bm, long b_rs, long b_bs,
    float* __restrict__ C, long c_rs, long c_bs,
    const float* __restrict__ bias, const float* __restrict__ bias2,
    int M, int N, int K)
{
    __shared__ float As[16][68];
    __shared__ float Bs[16][68];
    const int bb = blockIdx.z;
    const float* Ab = A + (long)bb * a_bs;
    const float* Bb = Bm + (long)bb * b_bs;
    float* Cb = C + (long)bb * c_bs;
    const int m0 = blockIdx.y * 64, n0 = blockIdx.x * 64;
    const int tid = threadIdx.x;
    const int tx = tid & 15, ty = tid >> 4;
    const int lr = tid >> 2;          // tile row 0..63
    const int lk = (tid & 3) << 2;    // k offset 0..12

    long arow;
    {
        int m = m0 + lr;
        if (REMAP_A) arow = (long)((m % S_) * B_ + (m / S_)) * a_rs;
        else         arow = (long)m * a_rs;
    }
    const long brow = (long)(n0 + lr) * b_rs;

    float acc[4][4] = {};
    for (int k0 = 0; k0 < K; k0 += 16) {
        float4 av = *(const float4*)(Ab + arow + k0 + lk);
        float4 bv = *(const float4*)(Bb + brow + k0 + lk);
        As[lk + 0][lr] = av.x; As[lk + 1][lr] = av.y;
        As[lk + 2][lr] = av.z; As[lk + 3][lr] = av.w;
        Bs[lk + 0][lr] = bv.x; Bs[lk + 1][lr] = bv.y;
        Bs[lk + 2][lr] = bv.z; Bs[lk + 3][lr] = bv.w;
        __syncthreads();
#pragma unroll
        for (int kk = 0; kk < 16; ++kk) {
            float4 a = *(const float4*)&As[kk][ty << 2];
            float4 b = *(const float4*)&Bs[kk][tx << 2];
            acc[0][0] += a.x * b.x; acc[0][1] += a.x * b.y; acc[0][2] += a.x * b.z; acc[0][3] += a.x * b.w;
            acc[1][0] += a.y * b.x; acc[1][1] += a.y * b.y; acc[1][2] += a.y * b.z; acc[1][3] += a.y * b.w;
            acc[2][0] += a.z * b.x; acc[2][1] += a.z * b.y; acc[2][2] += a.z * b.z; acc[2][3] += a.z * b.w;
            acc[3][0] += a.w * b.x; acc[3][1] += a.w * b.y; acc[3][2] += a.w * b.z; acc[3][3] += a.w * b.w;
        }
        __syncthreads();
    }
#pragma unroll
    for (int i = 0; i < 4; ++i) {
        const int m = m0 + (ty << 2) + i;
#pragma unroll
        for (int j = 0; j < 4; ++j) {
            const int n = n0 + (tx << 2) + j;
            float v = acc[i][j];
            if (EPI == 1) v = tanhf(v + bias[n]);
            else if (EPI == 2) v += bias[n] + bias2[n];
            Cb[(long)m * c_rs + n] = v;
        }
    }
}

// ---------------------------------------------------------------------------
// Tiled fp32 GEMM:  C[m][n] = sum_k A(k,m) * B(n,k)
// A layout KM ([K][M], k stride a_ks), B layout NK.  No epilogue.
// ---------------------------------------------------------------------------
__global__ __launch_bounds__(256) void gemm_km_nk(
    const float* __restrict__ A, long a_ks, long a_bs,
    const float* __restrict__ Bm, long b_rs, long b_bs,
    float* __restrict__ C, long c_rs, long c_bs,
    int M, int N, int K)
{
    __shared__ float As[16][68];
    __shared__ float Bs[16][68];
    const int bb = blockIdx.z;
    const float* Ab = A + (long)bb * a_bs;
    const float* Bb = Bm + (long)bb * b_bs;
    float* Cb = C + (long)bb * c_bs;
    const int m0 = blockIdx.y * 64, n0 = blockIdx.x * 64;
    const int tid = threadIdx.x;
    const int tx = tid & 15, ty = tid >> 4;
    const int lr = tid >> 2;            // B tile row (n) 0..63
    const int lk = (tid & 3) << 2;      // B k offset
    const int alk = tid >> 4;           // A k row 0..15
    const int alm = (tid & 15) << 2;    // A m offset
    const long brow = (long)(n0 + lr) * b_rs;

    float acc[4][4] = {};
    for (int k0 = 0; k0 < K; k0 += 16) {
        float4 av = *(const float4*)(Ab + (long)(k0 + alk) * a_ks + m0 + alm);
        *(float4*)&As[alk][alm] = av;
        float4 bv = *(const float4*)(Bb + brow + k0 + lk);
        Bs[lk + 0][lr] = bv.x; Bs[lk + 1][lr] = bv.y;
        Bs[lk + 2][lr] = bv.z; Bs[lk + 3][lr] = bv.w;
        __syncthreads();
#pragma unroll
        for (int kk = 0; kk < 16; ++kk) {
            float4 a = *(const float4*)&As[kk][ty << 2];
            float4 b = *(const float4*)&Bs[kk][tx << 2];
            acc[0][0] += a.x * b.x; acc[0][1] += a.x * b.y; acc[0][2] += a.x * b.z; acc[0][3] += a.x * b.w;
            acc[1][0] += a.y * b.x; acc[1][1] += a.y * b.y; acc[1][2] += a.y * b.z; acc[1][3] += a.y * b.w;
            acc[2][0] += a.z * b.x; acc[2][1] += a.z * b.y; acc[2][2] += a.z * b.z; acc[2][3] += a.z * b.w;
            acc[3][0] += a.w * b.x; acc[3][1] += a.w * b.y; acc[3][2] += a.w * b.z; acc[3][3] += a.w * b.w;
        }
        __syncthreads();
    }
#pragma unroll
    for (int i = 0; i < 4; ++i) {
        const int m = m0 + (ty << 2) + i;
#pragma unroll
        for (int j = 0; j < 4; ++j) {
            const int n = n0 + (tx << 2) + j;
            Cb[(long)m * c_rs + n] = acc[i][j];
        }
    }
}

// ---------------------------------------------------------------------------
// Softmax over r (last axis, contiguous, 512 elems): one wave per row, in-place
// ---------------------------------------------------------------------------
__global__ __launch_bounds__(256) void softmax_rows(float* __restrict__ l)
{
    const int lane = threadIdx.x & 63;
    const int wv = threadIdx.x >> 6;
    const long row = (long)blockIdx.x * 4 + wv;
    float* p = l + row * R_;
    float4 v0 = ((const float4*)p)[lane * 2];
    float4 v1 = ((const float4*)p)[lane * 2 + 1];
    float m = fmaxf(fmaxf(fmaxf(v0.x, v0.y), fmaxf(v0.z, v0.w)),
                    fmaxf(fmaxf(v1.x, v1.y), fmaxf(v1.z, v1.w)));
#pragma unroll
    for (int o = 32; o; o >>= 1) m = fmaxf(m, __shfl_xor(m, o));
    v0.x = __expf(v0.x - m); v0.y = __expf(v0.y - m);
    v0.z = __expf(v0.z - m); v0.w = __expf(v0.w - m);
    v1.x = __expf(v1.x - m); v1.y = __expf(v1.y - m);
    v1.z = __expf(v1.z - m); v1.w = __expf(v1.w - m);
    float s = v0.x + v0.y + v0.z + v0.w + v1.x + v1.y + v1.z + v1.w;
#pragma unroll
    for (int o = 32; o; o >>= 1) s += __shfl_xor(s, o);
    const float inv = 1.f / s;
    v0.x *= inv; v0.y *= inv; v0.z *= inv; v0.w *= inv;
    v1.x *= inv; v1.y *= inv; v1.z *= inv; v1.w *= inv;
    ((float4*)p)[lane * 2] = v0;
    ((float4*)p)[lane * 2 + 1] = v1;
}

// ---------------------------------------------------------------------------
// Softmax over s (axis 1, stride R): 512 threads = 128 cols x 4 s-groups,
// LDS reduce across the 4 partials, 3 coalesced passes.
// ---------------------------------------------------------------------------
__global__ __launch_bounds__(512) void softmax_cols(const float* __restrict__ l,
                                                    float* __restrict__ as_)
{
    const int b = blockIdx.y;
    const int rl = threadIdx.x & 127;
    const int r = blockIdx.x * 128 + rl;
    const int sg = threadIdx.x >> 7;           // 0..3
    const int s0 = sg * (S_ / 4), s1 = s0 + S_ / 4;
    const float* base = l + (long)b * S_ * R_ + r;
    __shared__ float red[4][128];

    float pm = -1e30f;
    for (int s = s0; s < s1; ++s) pm = fmaxf(pm, base[(long)s * R_]);
    red[sg][rl] = pm;
    __syncthreads();
    const float m = fmaxf(fmaxf(red[0][rl], red[1][rl]), fmaxf(red[2][rl], red[3][rl]));
    __syncthreads();

    float ps = 0.f;
    for (int s = s0; s < s1; ++s) ps += __expf(base[(long)s * R_] - m);
    red[sg][rl] = ps;
    __syncthreads();
    const float inv = 1.f / (red[0][rl] + red[1][rl] + red[2][rl] + red[3][rl]);

    float* ob = as_ + (long)b * S_ * R_ + r;
    for (int s = s0; s < s1; ++s) ob[(long)s * R_] = __expf(base[(long)s * R_] - m) * inv;
}

// ---------------------------------------------------------------------------
// cat[b][h][s] = h_s[b][s][h]  (s_t half of cat_sc), 32x32 LDS tile transpose
// ---------------------------------------------------------------------------
__global__ __launch_bounds__(256) void transpose_hs(const float* __restrict__ hs,
                                                    float* __restrict__ cat)
{
    __shared__ float tile[32][33];
    const int b = blockIdx.z;
    const int s0 = blockIdx.x * 32, h0 = blockIdx.y * 32;
    const int tx = threadIdx.x, ty = threadIdx.y;
#pragma unroll
    for (int i = 0; i < 32; i += 8)
        tile[ty + i][tx] = hs[((long)b * S_ + s0 + ty + i) * H_ + h0 + tx];
    __syncthreads();
#pragma unroll
    for (int i = 0; i < 32; i += 8)
        cat[((long)b * 2 * H_ + h0 + ty + i) * S_ + s0 + tx] = tile[tx][ty + i];
}

// ---------------------------------------------------------------------------
// bin[t][b][0:1024] = c_r[b][t][:]; bin[t][b][1024:1536] = ref[t][b][:]
// ---------------------------------------------------------------------------
__global__ __launch_bounds__(256) void build_bin(const float* __restrict__ cr,
                                                 const float* __restrict__ ref,
                                                 float* __restrict__ bin)
{
    const long idx4 = (long)blockIdx.x * blockDim.x + threadIdx.x;
    if (idx4 >= (long)R_ * B_ * DIN_ / 4) return;
    const long f = idx4 * 4;
    const int d = (int)(f % DIN_);
    const long tb = f / DIN_;
    const int b = (int)(tb % B_);
    const int t = (int)(tb / B_);
    float4 v;
    if (d < 2 * H_) v = *(const float4*)(cr + ((long)b * R_ + t) * (2 * H_) + d);
    else            v = *(const float4*)(ref + ((long)t * B_ + b) * H_ + (d - 2 * H_));
    *(float4*)(bin + f) = v;
}

// ---------------------------------------------------------------------------
// Bi-LSTM scan, h-slice ownership: 32 blocks/dir x 256 threads, PLAIN launch
// (R3/R5 failed with absmax == max|ref| and out==0 signature across two
// different sync protocols -> diagnosis: silent hipLaunchCooperativeKernel
// rejection, not a race/math bug. We use no cooperative API; co-residency of
// 64 small blocks on 256 CUs is structural, and a scheduling failure would
// hang visibly, not corrupt silently.)
// Block (dir, j) owns h columns [8j, 8j+8) and ALL FOUR gate rows for them
// ({n, 256+n, 512+n, 768+n}) -> cell update is block-local; the only
// cross-block exchange is h itself (16 KB/dir/step, double-buffered).
// Sync: __threadfence + atomic-RMW sense barrier per dir (HW-proven in R2).
// LDS k-columns XOR-swizzled (c = k ^ (((k>>5)&7)<<2)) to kill the 8-way
// same-bank aliasing between stride-32 k-chunks.
// ---------------------------------------------------------------------------
#define NB_DIR 32

__device__ inline float sig_(float x) { return 1.f / (1.f + __expf(-x)); }
__device__ inline float tanh_(float x) {
    float ax = fabsf(x);
    float t = 1.f - 2.f / (1.f + __expf(2.f * ax));
    return copysignf(t, x);
}

__device__ inline void dirBarrier(unsigned* bar, int nblocks)
{
    __syncthreads();
    if (threadIdx.x == 0) {
        unsigned gen = __hip_atomic_load(bar + 1, __ATOMIC_RELAXED, __HIP_MEMORY_SCOPE_AGENT);
        unsigned old = __hip_atomic_fetch_add(bar, 1u, __ATOMIC_ACQ_REL, __HIP_MEMORY_SCOPE_AGENT);
        if (old == (unsigned)(nblocks - 1)) {
            __hip_atomic_store(bar, 0u, __ATOMIC_RELAXED, __HIP_MEMORY_SCOPE_AGENT);
            __hip_atomic_fetch_add(bar + 1, 1u, __ATOMIC_RELEASE, __HIP_MEMORY_SCOPE_AGENT);
        } else {
            while (__hip_atomic_load(bar + 1, __ATOMIC_ACQUIRE, __HIP_MEMORY_SCOPE_AGENT) == gen)
                __builtin_amdgcn_s_sleep(2);
        }
    }
    __syncthreads();
}

__global__ __launch_bounds__(256) void lstm_scan(
    const float* __restrict__ xg_f, const float* __restrict__ xg_b,
    const float* __restrict__ Whh_f, const float* __restrict__ Whh_b,
    float* __restrict__ out, float* __restrict__ hbuf, unsigned* __restrict__ bar)
{
    const int blk = blockIdx.x;
    const int dir = blk >> 5;
    const int j = blk & 31;
    const int n0 = j * 8;
    const float* xg  = dir ? xg_b : xg_f;
    const float* Whh = dir ? Whh_b : Whh_f;
    float* hb = hbuf + dir * (2 * B_ * HD_);
    unsigned* mybar = bar + dir * 64;

    __shared__ float W_lds[32][260];   // row r = gate*8+col, k-swizzled
    __shared__ float h_lds[16][260];   // k-swizzled
    __shared__ float g_lds[32][17];    // reduced gate values [r][b]

    const int tid = threadIdx.x;

    // Load W slice once: LDS row r=gate*8+col <- Whh[gate*256 + n0 + col][:]
    for (int idx = tid; idx < 32 * 64; idx += 256) {
        const int r = idx >> 6;
        const int k4 = (idx & 63) << 2;
        const int gate = r >> 3, col = r & 7;
        float4 v = *(const float4*)(Whh + (long)(gate * 256 + n0 + col) * HD_ + k4);
        const int c = k4 ^ (((k4 >> 5) & 7) << 2);
        *(float4*)&W_lds[r][c] = v;
    }

    // dot-phase mapping: 256 thr = 32 groups (4b x 4r tile) x 8 k-splits
    const int group = tid >> 3, ks = tid & 7;
    const int b0 = (group & 3) << 2;
    const int r0 = (group >> 2) << 2;       // rows r0..r0+3, single gate each
    const int kbase = ks << 5;
    // cell-phase mapping (tid < 128): one (b, col) element
    const int cb = tid & 15, cc = tid >> 4;
    float c_reg = 0.f;
    __syncthreads();

    for (int t = 0; t < R_; ++t) {
        const int tt = dir ? (R_ - 1 - t) : t;

        // stage h_t (parity t&1) into LDS, k-swizzled; prefetch xg
        const float* hsrc = hb + (t & 1) * (B_ * HD_);
#pragma unroll
        for (int i = 0; i < 4; ++i) {
            const int f = i * 256 + tid;          // float4 index
            const int b = f >> 6, k4 = (f & 63) << 2;
            float4 v = *(const float4*)(hsrc + b * HD_ + k4);
            const int c = k4 ^ (((k4 >> 5) & 7) << 2);
            *(float4*)&h_lds[b][c] = v;
        }
        float xgv0 = 0.f, xgv1 = 0.f, xgv2 = 0.f, xgv3 = 0.f;
        if (tid < 128) {
            const long xb = ((long)tt * B_ + cb) * G_ + n0 + cc;
            xgv0 = xg[xb + 0 * HD_];
            xgv1 = xg[xb + 1 * HD_];
            xgv2 = xg[xb + 2 * HD_];
            xgv3 = xg[xb + 3 * HD_];
        }
        __syncthreads();

        // 4x4 register-tile dot over this thread's 32-wide k chunk
        float acc[4][4] = {};
#pragma unroll
        for (int kk = 0; kk < 32; kk += 4) {
            const int c = kbase + (kk ^ (ks << 2));
            float4 h0 = *(const float4*)&h_lds[b0 + 0][c];
            float4 h1 = *(const float4*)&h_lds[b0 + 1][c];
            float4 h2 = *(const float4*)&h_lds[b0 + 2][c];
            float4 h3 = *(const float4*)&h_lds[b0 + 3][c];
            float4 w0 = *(const float4*)&W_lds[r0 + 0][c];
            float4 w1 = *(const float4*)&W_lds[r0 + 1][c];
            float4 w2 = *(const float4*)&W_lds[r0 + 2][c];
            float4 w3 = *(const float4*)&W_lds[r0 + 3][c];
#define DOT4(hv, wv) (hv.x * wv.x + hv.y * wv.y + hv.z * wv.z + hv.w * wv.w)
            acc[0][0] += DOT4(h0, w0); acc[0][1] += DOT4(h1, w0);
            acc[0][2] += DOT4(h2, w0); acc[0][3] += DOT4(h3, w0);
            acc[1][0] += DOT4(h0, w1); acc[1][1] += DOT4(h1, w1);
            acc[1][2] += DOT4(h2, w1); acc[1][3] += DOT4(h3, w1);
            acc[2][0] += DOT4(h0, w2); acc[2][1] += DOT4(h1, w2);
            acc[2][2] += DOT4(h2, w2); acc[2][3] += DOT4(h3, w2);
            acc[3][0] += DOT4(h0, w3); acc[3][1] += DOT4(h1, w3);
            acc[3][2] += DOT4(h2, w3); acc[3][3] += DOT4(h3, w3);
#undef DOT4
        }
        // reduce the 8 k-splits (lanes g*8 .. g*8+7)
#pragma unroll
        for (int off = 1; off < 8; off <<= 1) {
#pragma unroll
            for (int ri = 0; ri < 4; ++ri)
#pragma unroll
                for (int bi = 0; bi < 4; ++bi)
                    acc[ri][bi] += __shfl_xor(acc[ri][bi], off);
        }
        if (ks == 0) {
#pragma unroll
            for (int ri = 0; ri < 4; ++ri)
#pragma unroll
                for (int bi = 0; bi < 4; ++bi)
                    g_lds[r0 + ri][b0 + bi] = acc[ri][bi];
        }
        __syncthreads();

        // cell update (block-local: all 4 gates of (b, n0+cc) are here)
        if (tid < 128) {
            const float iv = g_lds[0 * 8 + cc][cb] + xgv0;
            const float fv = g_lds[1 * 8 + cc][cb] + xgv1;
            const float gv = g_lds[2 * 8 + cc][cb] + xgv2;
            const float ov = g_lds[3 * 8 + cc][cb] + xgv3;
            c_reg = sig_(fv) * c_reg + sig_(iv) * tanh_(gv);
            const float h = sig_(ov) * tanh_(c_reg);
            out[((long)tt * B_ + cb) * (2 * HD_) + dir * HD_ + n0 + cc] = h;
            hb[((t + 1) & 1) * (B_ * HD_) + cb * HD_ + n0 + cc] = h;
        }
        __threadfence();             // agent-scope fence: h writes -> LLC (proven in R2)
        dirBarrier(mybar, NB_DIR);   // acq_rel RMW + acquire polls (proven in R2)
    }
}

// ---------------------------------------------------------------------------
extern "C" void kernel_launch(void* const* d_in, const int* in_sizes, int n_in,
                              void* d_out, int out_size, void* d_ws, size_t ws_size,
                              hipStream_t stream)
{
    const float* src  = (const float*)d_in[1];   // [S][B][H]
    const float* ref  = (const float*)d_in[2];   // [R][B][H]
    const float* Wref = (const float*)d_in[3];   // [H][H]
    const float* bref = (const float*)d_in[4];   // [H]
    const float* Wihf = (const float*)d_in[5];   // [G][DIN]
    const float* Whhf = (const float*)d_in[6];   // [G][HD]
    const float* bihf = (const float*)d_in[7];
    const float* bhhf = (const float*)d_in[8];
    const float* Wihb = (const float*)d_in[9];
    const float* Whhb = (const float*)d_in[10];
    const float* bihb = (const float*)d_in[11];
    const float* bhhb = (const float*)d_in[12];
    float* out = (float*)d_out;                  // [R][B][2*HD]

    float* ws = (float*)d_ws;
    // workspace layout (floats), with aliasing:
    float* hs  = ws + 0L;                         // 8388608   [B][S][H]
    float* l   = ws + 8388608L;                   // 8388608   [B][S][R] (a_r in place)
    float* as_ = ws + 16777216L;                  // 8388608   [B][S][R]
    float* cat = ws + 25165824L;                  // 16777216  [B][2H][S]
    float* cr  = hs;                              // 8388608   [B][R][2H]  (hs dead after step 4)
    float* bin = cat;                             // 12582912  [T][B][DIN] (cat dead after step 6)
    float* xgf = l;                               // 8388608   [T][B][G]   (l dead after step 6)
    float* xgb = as_;                             // 8388608   [T][B][G]   (as_ dead after step 5)
    float* hbuf = ws + 41943040L;                 // 16384     2 dir x 2 parity x [B][HD]
    unsigned* bar = (unsigned*)(ws + 41959424L);  // 128 u32   2 dir x 64 barrier state

    // zero hbuf (h_0 = 0) + barrier state, every launch
    hipMemsetAsync(hbuf, 0, 16384 * 4 + 512, stream);

    // 1) h_s = tanh(src . Wref^T + bref)   [B*S, 512] k=512
    gemm_mk_nk<1, 1><<<dim3(8, 256, 1), 256, 0, stream>>>(
        src, H_, 0, Wref, H_, 0, hs, H_, 0, bref, nullptr, B_ * S_, H_, H_);

    // 2) l[b] = h_s[b] . h_r[b]^T   M=1024 N=512 K=512, batched over b
    gemm_mk_nk<0, 0><<<dim3(8, 16, B_), 256, 0, stream>>>(
        hs, H_, (long)S_ * H_, ref, (long)B_ * H_, H_, l, R_, (long)S_ * R_,
        nullptr, nullptr, S_, R_, H_);

    // 3) a_s = softmax over s (columns), then a_r = softmax over r in place
    softmax_cols<<<dim3(R_ / 128, B_), 512, 0, stream>>>(l, as_);
    softmax_rows<<<(B_ * S_) / 4, 256, 0, stream>>>(l);

    // 4) cat rows 0..511 = h_s transposed
    transpose_hs<<<dim3(S_ / 32, H_ / 32, B_), dim3(32, 8), 0, stream>>>(hs, cat);

    // 5) cat rows 512..1023: c_s[b,h,s] = sum_r ref[r,b,h]*a_s[b,s,r]
    gemm_km_nk<<<dim3(16, 8, B_), 256, 0, stream>>>(
        ref, (long)B_ * H_, H_, as_, R_, (long)S_ * R_,
        cat + (long)H_ * S_, S_, (long)2 * H_ * S_, H_, S_, R_);

    // 6) c_r[b,r,k] = sum_s cat[b,k,s]*a_r[b,s,r]   M=512 N=1024 K=1024
    gemm_km_nk<<<dim3(16, 8, B_), 256, 0, stream>>>(
        l, R_, (long)S_ * R_, cat, S_, (long)2 * H_ * S_,
        cr, 2 * H_, (long)R_ * 2 * H_, R_, 2 * H_, S_);

    // 7) bilstm_in
    build_bin<<<(R_ * B_ * DIN_ / 4 + 255) / 256, 256, 0, stream>>>(cr, ref, bin);

    // 8) xg = bin . W_ih^T + b_ih + b_hh  (both directions)
    gemm_mk_nk<2, 0><<<dim3(16, 128, 1), 256, 0, stream>>>(
        bin, DIN_, 0, Wihf, DIN_, 0, xgf, G_, 0, bihf, bhhf, R_ * B_, G_, DIN_);
    gemm_mk_nk<2, 0><<<dim3(16, 128, 1), 256, 0, stream>>>(
        bin, DIN_, 0, Wihb, DIN_, 0, xgb, G_, 0, bihb, bhhb, R_ * B_, G_, DIN_);

    // 9) bi-LSTM scan: PLAIN launch (no cooperative API used inside; 64 blocks
    //    on 256 CUs are trivially co-resident; a scheduling failure would hang,
    //    not silently corrupt)
    lstm_scan<<<dim3(2 * NB_DIR), dim3(256), 0, stream>>>(
        xgf, xgb, Whhf, Whhb, out, hbuf, bar);
}

// Round 7
// 5439.407 us; speedup vs baseline: 3.4950x; 1.4555x over previous
//
#include <hip/hip_runtime.h>
#include <math.h>

#define B_   16
#define S_   1024
#define R_   512
#define H_   512
#define HD_  256
#define G_   1024
#define DIN_ 1536

// ---------------------------------------------------------------------------
// Tiled fp32 GEMM:  C[m][n] = sum_k A(m,k) * B(n,k)
// A layout MK (row-major [M][K], row stride a_rs), optional row remap for step1.
// B layout NK (row-major [N][K], row stride b_rs).
// EPI: 0 = none, 1 = tanh(x + bias[n]), 2 = x + bias[n] + bias2[n]
// ---------------------------------------------------------------------------
template<int EPI, int REMAP_A>
__global__ __launch_bounds__(256) void gemm_mk_nk(
    const float* __restrict__ A, long a_rs, long a_bs,
    const float* __restrict__ Bm, long b_rs, long b_bs,
    float* __restrict__ C, long c_rs, long c_bs,
    const float* __restrict__ bias, const float* __restrict__ bias2,
    int M, int N, int K)
{
    __shared__ float As[16][68];
    __shared__ float Bs[16][68];
    const int bb = blockIdx.z;
    const float* Ab = A + (long)bb * a_bs;
    const float* Bb = Bm + (long)bb * b_bs;
    float* Cb = C + (long)bb * c_bs;
    const int m0 = blockIdx.y * 64, n0 = blockIdx.x * 64;
    const int tid = threadIdx.x;
    const int tx = tid & 15, ty = tid >> 4;
    const int lr = tid >> 2;          // tile row 0..63
    const int lk = (tid & 3) << 2;    // k offset 0..12

    long arow;
    {
        int m = m0 + lr;
        if (REMAP_A) arow = (long)((m % S_) * B_ + (m / S_)) * a_rs;
        else         arow = (long)m * a_rs;
    }
    const long brow = (long)(n0 + lr) * b_rs;

    float acc[4][4] = {};
    for (int k0 = 0; k0 < K; k0 += 16) {
        float4 av = *(const float4*)(Ab + arow + k0 + lk);
        float4 bv = *(const float4*)(Bb + brow + k0 + lk);
        As[lk + 0][lr] = av.x; As[lk + 1][lr] = av.y;
        As[lk + 2][lr] = av.z; As[lk + 3][lr] = av.w;
        Bs[lk + 0][lr] = bv.x; Bs[lk + 1][lr] = bv.y;
        Bs[lk + 2][lr] = bv.z; Bs[lk + 3][lr] = bv.w;
        __syncthreads();
#pragma unroll
        for (int kk = 0; kk < 16; ++kk) {
            float4 a = *(const float4*)&As[kk][ty << 2];
            float4 b = *(const float4*)&Bs[kk][tx << 2];
            acc[0][0] += a.x * b.x; acc[0][1] += a.x * b.y; acc[0][2] += a.x * b.z; acc[0][3] += a.x * b.w;
            acc[1][0] += a.y * b.x; acc[1][1] += a.y * b.y; acc[1][2] += a.y * b.z; acc[1][3] += a.y * b.w;
            acc[2][0] += a.z * b.x; acc[2][1] += a.z * b.y; acc[2][2] += a.z * b.z; acc[2][3] += a.z * b.w;
            acc[3][0] += a.w * b.x; acc[3][1] += a.w * b.y; acc[3][2] += a.w * b.z; acc[3][3] += a.w * b.w;
        }
        __syncthreads();
    }
#pragma unroll
    for (int i = 0; i < 4; ++i) {
        const int m = m0 + (ty << 2) + i;
#pragma unroll
        for (int j = 0; j < 4; ++j) {
            const int n = n0 + (tx << 2) + j;
            float v = acc[i][j];
            if (EPI == 1) v = tanhf(v + bias[n]);
            else if (EPI == 2) v += bias[n] + bias2[n];
            Cb[(long)m * c_rs + n] = v;
        }
    }
}

// ---------------------------------------------------------------------------
// Tiled fp32 GEMM:  C[m][n] = sum_k A(k,m) * B(n,k)
// A layout KM ([K][M], k stride a_ks), B layout NK.  No epilogue.
// ---------------------------------------------------------------------------
__global__ __launch_bounds__(256) void gemm_km_nk(
    const float* __restrict__ A, long a_ks, long a_bs,
    const float* __restrict__ Bm, long b_rs, long b_bs,
    float* __restrict__ C, long c_rs, long c_bs,
    int M, int N, int K)
{
    __shared__ float As[16][68];
    __shared__ float Bs[16][68];
    const int bb = blockIdx.z;
    const float* Ab = A + (long)bb * a_bs;
    const float* Bb = Bm + (long)bb * b_bs;
    float* Cb = C + (long)bb * c_bs;
    const int m0 = blockIdx.y * 64, n0 = blockIdx.x * 64;
    const int tid = threadIdx.x;
    const int tx = tid & 15, ty = tid >> 4;
    const int lr = tid >> 2;            // B tile row (n) 0..63
    const int lk = (tid & 3) << 2;      // B k offset
    const int alk = tid >> 4;           // A k row 0..15
    const int alm = (tid & 15) << 2;    // A m offset
    const long brow = (long)(n0 + lr) * b_rs;

    float acc[4][4] = {};
    for (int k0 = 0; k0 < K; k0 += 16) {
        float4 av = *(const float4*)(Ab + (long)(k0 + alk) * a_ks + m0 + alm);
        *(float4*)&As[alk][alm] = av;
        float4 bv = *(const float4*)(Bb + brow + k0 + lk);
        Bs[lk + 0][lr] = bv.x; Bs[lk + 1][lr] = bv.y;
        Bs[lk + 2][lr] = bv.z; Bs[lk + 3][lr] = bv.w;
        __syncthreads();
#pragma unroll
        for (int kk = 0; kk < 16; ++kk) {
            float4 a = *(const float4*)&As[kk][ty << 2];
            float4 b = *(const float4*)&Bs[kk][tx << 2];
            acc[0][0] += a.x * b.x; acc[0][1] += a.x * b.y; acc[0][2] += a.x * b.z; acc[0][3] += a.x * b.w;
            acc[1][0] += a.y * b.x; acc[1][1] += a.y * b.y; acc[1][2] += a.y * b.z; acc[1][3] += a.y * b.w;
            acc[2][0] += a.z * b.x; acc[2][1] += a.z * b.y; acc[2][2] += a.z * b.z; acc[2][3] += a.z * b.w;
            acc[3][0] += a.w * b.x; acc[3][1] += a.w * b.y; acc[3][2] += a.w * b.z; acc[3][3] += a.w * b.w;
        }
        __syncthreads();
    }
#pragma unroll
    for (int i = 0; i < 4; ++i) {
        const int m = m0 + (ty << 2) + i;
#pragma unroll
        for (int j = 0; j < 4; ++j) {
            const int n = n0 + (tx << 2) + j;
            Cb[(long)m * c_rs + n] = acc[i][j];
        }
    }
}

// ---------------------------------------------------------------------------
// Softmax over r (last axis, contiguous, 512 elems): one wave per row, in-place
// ---------------------------------------------------------------------------
__global__ __launch_bounds__(256) void softmax_rows(float* __restrict__ l)
{
    const int lane = threadIdx.x & 63;
    const int wv = threadIdx.x >> 6;
    const long row = (long)blockIdx.x * 4 + wv;
    float* p = l + row * R_;
    float4 v0 = ((const float4*)p)[lane * 2];
    float4 v1 = ((const float4*)p)[lane * 2 + 1];
    float m = fmaxf(fmaxf(fmaxf(v0.x, v0.y), fmaxf(v0.z, v0.w)),
                    fmaxf(fmaxf(v1.x, v1.y), fmaxf(v1.z, v1.w)));
#pragma unroll
    for (int o = 32; o; o >>= 1) m = fmaxf(m, __shfl_xor(m, o));
    v0.x = __expf(v0.x - m); v0.y = __expf(v0.y - m);
    v0.z = __expf(v0.z - m); v0.w = __expf(v0.w - m);
    v1.x = __expf(v1.x - m); v1.y = __expf(v1.y - m);
    v1.z = __expf(v1.z - m); v1.w = __expf(v1.w - m);
    float s = v0.x + v0.y + v0.z + v0.w + v1.x + v1.y + v1.z + v1.w;
#pragma unroll
    for (int o = 32; o; o >>= 1) s += __shfl_xor(s, o);
    const float inv = 1.f / s;
    v0.x *= inv; v0.y *= inv; v0.z *= inv; v0.w *= inv;
    v1.x *= inv; v1.y *= inv; v1.z *= inv; v1.w *= inv;
    ((float4*)p)[lane * 2] = v0;
    ((float4*)p)[lane * 2 + 1] = v1;
}

// ---------------------------------------------------------------------------
// Softmax over s (axis 1, stride R): 512 threads = 128 cols x 4 s-groups,
// LDS reduce across the 4 partials, 3 coalesced passes.
// ---------------------------------------------------------------------------
__global__ __launch_bounds__(512) void softmax_cols(const float* __restrict__ l,
                                                    float* __restrict__ as_)
{
    const int b = blockIdx.y;
    const int rl = threadIdx.x & 127;
    const int r = blockIdx.x * 128 + rl;
    const int sg = threadIdx.x >> 7;           // 0..3
    const int s0 = sg * (S_ / 4), s1 = s0 + S_ / 4;
    const float* base = l + (long)b * S_ * R_ + r;
    __shared__ float red[4][128];

    float pm = -1e30f;
    for (int s = s0; s < s1; ++s) pm = fmaxf(pm, base[(long)s * R_]);
    red[sg][rl] = pm;
    __syncthreads();
    const float m = fmaxf(fmaxf(red[0][rl], red[1][rl]), fmaxf(red[2][rl], red[3][rl]));
    __syncthreads();

    float ps = 0.f;
    for (int s = s0; s < s1; ++s) ps += __expf(base[(long)s * R_] - m);
    red[sg][rl] = ps;
    __syncthreads();
    const float inv = 1.f / (red[0][rl] + red[1][rl] + red[2][rl] + red[3][rl]);

    float* ob = as_ + (long)b * S_ * R_ + r;
    for (int s = s0; s < s1; ++s) ob[(long)s * R_] = __expf(base[(long)s * R_] - m) * inv;
}

// ---------------------------------------------------------------------------
// cat[b][h][s] = h_s[b][s][h]  (s_t half of cat_sc), 32x32 LDS tile transpose
// ---------------------------------------------------------------------------
__global__ __launch_bounds__(256) void transpose_hs(const float* __restrict__ hs,
                                                    float* __restrict__ cat)
{
    __shared__ float tile[32][33];
    const int b = blockIdx.z;
    const int s0 = blockIdx.x * 32, h0 = blockIdx.y * 32;
    const int tx = threadIdx.x, ty = threadIdx.y;
#pragma unroll
    for (int i = 0; i < 32; i += 8)
        tile[ty + i][tx] = hs[((long)b * S_ + s0 + ty + i) * H_ + h0 + tx];
    __syncthreads();
#pragma unroll
    for (int i = 0; i < 32; i += 8)
        cat[((long)b * 2 * H_ + h0 + ty + i) * S_ + s0 + tx] = tile[tx][ty + i];
}

// ---------------------------------------------------------------------------
// bin[t][b][0:1024] = c_r[b][t][:]; bin[t][b][1024:1536] = ref[t][b][:]
// ---------------------------------------------------------------------------
__global__ __launch_bounds__(256) void build_bin(const float* __restrict__ cr,
                                                 const float* __restrict__ ref,
                                                 float* __restrict__ bin)
{
    const long idx4 = (long)blockIdx.x * blockDim.x + threadIdx.x;
    if (idx4 >= (long)R_ * B_ * DIN_ / 4) return;
    const long f = idx4 * 4;
    const int d = (int)(f % DIN_);
    const long tb = f / DIN_;
    const int b = (int)(tb % B_);
    const int t = (int)(tb / B_);
    float4 v;
    if (d < 2 * H_) v = *(const float4*)(cr + ((long)b * R_ + t) * (2 * H_) + d);
    else            v = *(const float4*)(ref + ((long)t * B_ + b) * H_ + (d - 2 * H_));
    *(float4*)(bin + f) = v;
}

// ---------------------------------------------------------------------------
// Bi-LSTM scan, h-slice ownership: 32 blocks/dir x 256 threads, PLAIN launch.
// Block (dir, j) owns h columns [8j, 8j+8) and ALL FOUR gate rows for them.
// Sync (R7): monotonic per-block FLAGS on separate cachelines.
//   writer: h stores -> __syncthreads (drains vmcnt all waves) -> tid0:
//           __threadfence (one wbl2 covers the XCD-shared L2) -> relaxed
//           flag store (64B-strided line per block).
//   reader: prefetch xg (flag-independent) -> wave0 polls all 32 flags with
//           one 32-lane coherent load/iter -> __syncthreads -> acquire-agent
//           fence (buffer_inv) -> stage h.
// Replaces R6's counting barrier whose 32 serialized same-line LLC RMWs
// (~6.4us/step) dominated the 12.6us/step critical path. Flag stores are
// parallel; polls are read-shared. WAR on the h double buffer is excluded by
// the one-sync-per-step ordering (re-derived: a block can only overwrite
// parity p at step u>=t+1 after ALL flags >= u, which postdates every
// step-t read of parity p).
// LDS k-columns XOR-swizzled (c = k ^ (((k>>5)&7)<<2)).
// ---------------------------------------------------------------------------
#define NB_DIR 32

__device__ inline float sig_(float x) { return 1.f / (1.f + __expf(-x)); }
__device__ inline float tanh_(float x) {
    float ax = fabsf(x);
    float t = 1.f - 2.f / (1.f + __expf(2.f * ax));
    return copysignf(t, x);
}

__global__ __launch_bounds__(256) void lstm_scan(
    const float* __restrict__ xg_f, const float* __restrict__ xg_b,
    const float* __restrict__ Whh_f, const float* __restrict__ Whh_b,
    float* __restrict__ out, float* __restrict__ hbuf, unsigned* __restrict__ flags)
{
    const int blk = blockIdx.x;
    const int dir = blk >> 5;
    const int j = blk & 31;
    const int n0 = j * 8;
    const float* xg  = dir ? xg_b : xg_f;
    const float* Whh = dir ? Whh_b : Whh_f;
    float* hb = hbuf + dir * (2 * B_ * HD_);
    unsigned* fl = flags + dir * (NB_DIR * 16);

    __shared__ float W_lds[32][260];   // row r = gate*8+col, k-swizzled
    __shared__ float h_lds[16][260];   // k-swizzled
    __shared__ float g_lds[32][17];    // reduced gate values [r][b]

    const int tid = threadIdx.x;

    // Load W slice once: LDS row r=gate*8+col <- Whh[gate*256 + n0 + col][:]
    for (int idx = tid; idx < 32 * 64; idx += 256) {
        const int r = idx >> 6;
        const int k4 = (idx & 63) << 2;
        const int gate = r >> 3, col = r & 7;
        float4 v = *(const float4*)(Whh + (long)(gate * 256 + n0 + col) * HD_ + k4);
        const int c = k4 ^ (((k4 >> 5) & 7) << 2);
        *(float4*)&W_lds[r][c] = v;
    }

    // dot-phase mapping: 256 thr = 32 groups (4b x 4r tile) x 8 k-splits
    const int group = tid >> 3, ks = tid & 7;
    const int b0 = (group & 3) << 2;
    const int r0 = (group >> 2) << 2;       // rows r0..r0+3, single gate each
    const int kbase = ks << 5;
    // cell-phase mapping (tid < 128): one (b, col) element
    const int cb = tid & 15, cc = tid >> 4;
    float c_reg = 0.f;
    __syncthreads();

    for (int t = 0; t < R_; ++t) {
        const int tt = dir ? (R_ - 1 - t) : t;

        // prefetch xg for this step (flag-independent; hides under the poll)
        float xgv0 = 0.f, xgv1 = 0.f, xgv2 = 0.f, xgv3 = 0.f;
        if (tid < 128) {
            const long xb = ((long)tt * B_ + cb) * G_ + n0 + cc;
            xgv0 = xg[xb + 0 * HD_];
            xgv1 = xg[xb + 1 * HD_];
            xgv2 = xg[xb + 2 * HD_];
            xgv3 = xg[xb + 3 * HD_];
        }

        // wait for h_t: all flags of this dir >= t
        if (t > 0) {
            if (tid < 64) {
                const unsigned* fp = &fl[(tid & 31) * 16];
                const bool mine = tid < NB_DIR;
                while (true) {
                    unsigned v = mine ? __hip_atomic_load(fp, __ATOMIC_RELAXED,
                                                          __HIP_MEMORY_SCOPE_AGENT)
                                      : 0xFFFFFFFFu;
                    if (__all(v >= (unsigned)t)) break;
                    __builtin_amdgcn_s_sleep(1);
                }
            }
            __syncthreads();
            __builtin_amdgcn_fence(__ATOMIC_ACQUIRE, "agent");   // inv L1/L2
        }

        // stage h_t (parity t&1) into LDS, k-swizzled
        const float* hsrc = hb + (t & 1) * (B_ * HD_);
#pragma unroll
        for (int i = 0; i < 4; ++i) {
            const int f = i * 256 + tid;          // float4 index
            const int b = f >> 6, k4 = (f & 63) << 2;
            float4 v = *(const float4*)(hsrc + b * HD_ + k4);
            const int c = k4 ^ (((k4 >> 5) & 7) << 2);
            *(float4*)&h_lds[b][c] = v;
        }
        __syncthreads();

        // 4x4 register-tile dot over this thread's 32-wide k chunk
        float acc[4][4] = {};
#pragma unroll
        for (int kk = 0; kk < 32; kk += 4) {
            const int c = kbase + (kk ^ (ks << 2));
            float4 h0 = *(const float4*)&h_lds[b0 + 0][c];
            float4 h1 = *(const float4*)&h_lds[b0 + 1][c];
            float4 h2 = *(const float4*)&h_lds[b0 + 2][c];
            float4 h3 = *(const float4*)&h_lds[b0 + 3][c];
            float4 w0 = *(const float4*)&W_lds[r0 + 0][c];
            float4 w1 = *(const float4*)&W_lds[r0 + 1][c];
            float4 w2 = *(const float4*)&W_lds[r0 + 2][c];
            float4 w3 = *(const float4*)&W_lds[r0 + 3][c];
#define DOT4(hv, wv) (hv.x * wv.x + hv.y * wv.y + hv.z * wv.z + hv.w * wv.w)
            acc[0][0] += DOT4(h0, w0); acc[0][1] += DOT4(h1, w0);
            acc[0][2] += DOT4(h2, w0); acc[0][3] += DOT4(h3, w0);
            acc[1][0] += DOT4(h0, w1); acc[1][1] += DOT4(h1, w1);
            acc[1][2] += DOT4(h2, w1); acc[1][3] += DOT4(h3, w1);
            acc[2][0] += DOT4(h0, w2); acc[2][1] += DOT4(h1, w2);
            acc[2][2] += DOT4(h2, w2); acc[2][3] += DOT4(h3, w2);
            acc[3][0] += DOT4(h0, w3); acc[3][1] += DOT4(h1, w3);
            acc[3][2] += DOT4(h2, w3); acc[3][3] += DOT4(h3, w3);
#undef DOT4
        }
        // reduce the 8 k-splits (lanes g*8 .. g*8+7)
#pragma unroll
        for (int off = 1; off < 8; off <<= 1) {
#pragma unroll
            for (int ri = 0; ri < 4; ++ri)
#pragma unroll
                for (int bi = 0; bi < 4; ++bi)
                    acc[ri][bi] += __shfl_xor(acc[ri][bi], off);
        }
        if (ks == 0) {
#pragma unroll
            for (int ri = 0; ri < 4; ++ri)
#pragma unroll
                for (int bi = 0; bi < 4; ++bi)
                    g_lds[r0 + ri][b0 + bi] = acc[ri][bi];
        }
        __syncthreads();

        // cell update (block-local: all 4 gates of (b, n0+cc) are here)
        if (tid < 128) {
            const float iv = g_lds[0 * 8 + cc][cb] + xgv0;
            const float fv = g_lds[1 * 8 + cc][cb] + xgv1;
            const float gv = g_lds[2 * 8 + cc][cb] + xgv2;
            const float ov = g_lds[3 * 8 + cc][cb] + xgv3;
            c_reg = sig_(fv) * c_reg + sig_(iv) * tanh_(gv);
            const float h = sig_(ov) * tanh_(c_reg);
            out[((long)tt * B_ + cb) * (2 * HD_) + dir * HD_ + n0 + cc] = h;
            hb[((t + 1) & 1) * (B_ * HD_) + cb * HD_ + n0 + cc] = h;
        }
        __syncthreads();   // drains all waves' h stores (vmcnt(0) before s_barrier)
        if (tid == 0) {
            __threadfence();   // wbl2: push this XCD's h lines to LLC
            __hip_atomic_store(&fl[j * 16], (unsigned)(t + 1), __ATOMIC_RELAXED,
                               __HIP_MEMORY_SCOPE_AGENT);
        }
    }
}

// ---------------------------------------------------------------------------
extern "C" void kernel_launch(void* const* d_in, const int* in_sizes, int n_in,
                              void* d_out, int out_size, void* d_ws, size_t ws_size,
                              hipStream_t stream)
{
    const float* src  = (const float*)d_in[1];   // [S][B][H]
    const float* ref  = (const float*)d_in[2];   // [R][B][H]
    const float* Wref = (const float*)d_in[3];   // [H][H]
    const float* bref = (const float*)d_in[4];   // [H]
    const float* Wihf = (const float*)d_in[5];   // [G][DIN]
    const float* Whhf = (const float*)d_in[6];   // [G][HD]
    const float* bihf = (const float*)d_in[7];
    const float* bhhf = (const float*)d_in[8];
    const float* Wihb = (const float*)d_in[9];
    const float* Whhb = (const float*)d_in[10];
    const float* bihb = (const float*)d_in[11];
    const float* bhhb = (const float*)d_in[12];
    float* out = (float*)d_out;                  // [R][B][2*HD]

    float* ws = (float*)d_ws;
    // workspace layout (floats), with aliasing:
    float* hs  = ws + 0L;                         // 8388608   [B][S][H]
    float* l   = ws + 8388608L;                   // 8388608   [B][S][R] (a_r in place)
    float* as_ = ws + 16777216L;                  // 8388608   [B][S][R]
    float* cat = ws + 25165824L;                  // 16777216  [B][2H][S]
    float* cr  = hs;                              // 8388608   [B][R][2H]  (hs dead after step 4)
    float* bin = cat;                             // 12582912  [T][B][DIN] (cat dead after step 6)
    float* xgf = l;                               // 8388608   [T][B][G]   (l dead after step 6)
    float* xgb = as_;                             // 8388608   [T][B][G]   (as_ dead after step 5)
    float* hbuf = ws + 41943040L;                 // 16384     2 dir x 2 parity x [B][HD]
    unsigned* flags = (unsigned*)(ws + 41959424L);// 1024 u32  2 dir x 32 x (64B stride)

    // zero hbuf (h_0 = 0) + flags, every launch
    hipMemsetAsync(hbuf, 0, 16384 * 4 + 4096, stream);

    // 1) h_s = tanh(src . Wref^T + bref)   [B*S, 512] k=512
    gemm_mk_nk<1, 1><<<dim3(8, 256, 1), 256, 0, stream>>>(
        src, H_, 0, Wref, H_, 0, hs, H_, 0, bref, nullptr, B_ * S_, H_, H_);

    // 2) l[b] = h_s[b] . h_r[b]^T   M=1024 N=512 K=512, batched over b
    gemm_mk_nk<0, 0><<<dim3(8, 16, B_), 256, 0, stream>>>(
        hs, H_, (long)S_ * H_, ref, (long)B_ * H_, H_, l, R_, (long)S_ * R_,
        nullptr, nullptr, S_, R_, H_);

    // 3) a_s = softmax over s (columns), then a_r = softmax over r in place
    softmax_cols<<<dim3(R_ / 128, B_), 512, 0, stream>>>(l, as_);
    softmax_rows<<<(B_ * S_) / 4, 256, 0, stream>>>(l);

    // 4) cat rows 0..511 = h_s transposed
    transpose_hs<<<dim3(S_ / 32, H_ / 32, B_), dim3(32, 8), 0, stream>>>(hs, cat);

    // 5) cat rows 512..1023: c_s[b,h,s] = sum_r ref[r,b,h]*a_s[b,s,r]
    gemm_km_nk<<<dim3(16, 8, B_), 256, 0, stream>>>(
        ref, (long)B_ * H_, H_, as_, R_, (long)S_ * R_,
        cat + (long)H_ * S_, S_, (long)2 * H_ * S_, H_, S_, R_);

    // 6) c_r[b,r,k] = sum_s cat[b,k,s]*a_r[b,s,r]   M=512 N=1024 K=1024
    gemm_km_nk<<<dim3(16, 8, B_), 256, 0, stream>>>(
        l, R_, (long)S_ * R_, cat, S_, (long)2 * H_ * S_,
        cr, 2 * H_, (long)R_ * 2 * H_, R_, 2 * H_, S_);

    // 7) bilstm_in
    build_bin<<<(R_ * B_ * DIN_ / 4 + 255) / 256, 256, 0, stream>>>(cr, ref, bin);

    // 8) xg = bin . W_ih^T + b_ih + b_hh  (both directions)
    gemm_mk_nk<2, 0><<<dim3(16, 128, 1), 256, 0, stream>>>(
        bin, DIN_, 0, Wihf, DIN_, 0, xgf, G_, 0, bihf, bhhf, R_ * B_, G_, DIN_);
    gemm_mk_nk<2, 0><<<dim3(16, 128, 1), 256, 0, stream>>>(
        bin, DIN_, 0, Wihb, DIN_, 0, xgb, G_, 0, bihb, bhhb, R_ * B_, G_, DIN_);

    // 9) bi-LSTM scan: plain launch, flag-synced
    lstm_scan<<<dim3(2 * NB_DIR), dim3(256), 0, stream>>>(
        xgf, xgb, Whhf, Whhb, out, hbuf, flags);
}